// Round 1
// baseline (75.544 us; speedup 1.0000x reference)
//
#include <hip/hip_runtime.h>
#include <hip/hip_bf16.h>
#include <stdint.h>

typedef unsigned short u16;
typedef unsigned int   u32;

#define N_ROWS 4096
#define DIM    512
#define NBLK   32          // N_ROWS / 128
#define MOD3   729         // 3^6
#define NLEV   6           // MAX_VALUATION + 1 levels used (v = 0..5)

typedef __attribute__((ext_vector_type(8))) __bf16 bf16x8;
typedef __attribute__((ext_vector_type(4))) float  f32x4;

// ---- workspace layout (byte offsets) ----
// zbf : N*D bf16            (4 MB)
// sq  : N float             (16 KB)
// r   : N int (idx % 729)   (16 KB)
// acc : float gsum[6]; u32 gcnt[6]
#define WS_ZBF 0
#define WS_SQ  (N_ROWS * DIM * 2)
#define WS_R   (WS_SQ + N_ROWS * 4)
#define WS_ACC (WS_R + N_ROWS * 4)

// ---------------------------------------------------------------------------
// Prep: f32 -> bf16 (RNE), row sum-of-squares, residues mod 729, zero accums.
// One wave per row; each lane handles 8 contiguous floats (two float4 loads,
// one 16B bf16 store).
// ---------------------------------------------------------------------------
__global__ __launch_bounds__(64)
void prep_kernel(const float* __restrict__ z, const int* __restrict__ idx,
                 u16* __restrict__ zbf, float* __restrict__ sq,
                 int* __restrict__ rres, float* __restrict__ gsum,
                 u32* __restrict__ gcnt)
{
    const int row  = blockIdx.x;
    const int lane = threadIdx.x;
    const float4* zr = reinterpret_cast<const float4*>(z + (size_t)row * DIM) + lane * 2;
    float4 v0 = zr[0], v1 = zr[1];
    float f[8] = {v0.x, v0.y, v0.z, v0.w, v1.x, v1.y, v1.z, v1.w};
    float ss = 0.f;
    u16 u[8];
#pragma unroll
    for (int k = 0; k < 8; ++k) {
        ss += f[k] * f[k];
        u32 b = __builtin_bit_cast(u32, f[k]);
        u[k] = (u16)((b + 0x7FFFu + ((b >> 16) & 1u)) >> 16);   // RNE to bf16
    }
    *reinterpret_cast<uint4*>(zbf + (size_t)row * DIM + lane * 8) =
        *reinterpret_cast<const uint4*>(u);
#pragma unroll
    for (int off = 32; off > 0; off >>= 1) ss += __shfl_down(ss, off, 64);
    if (lane == 0) {
        sq[row]   = ss;
        rres[row] = idx[row] % MOD3;   // idx >= 0
    }
    if (row == 0 && lane < NLEV) { gsum[lane] = 0.f; gcnt[lane] = 0u; }
}

// ---------------------------------------------------------------------------
// Main: one block per upper-triangular 128x128 tile pair (bi <= bj).
// 4 waves (2x2), each wave owns a 64x64 output quadrant = 4x4 MFMA 16x16x32
// fragments. A/B tiles staged via global_load_lds width=16. Fused epilogue:
// dist -> valuation LUT -> per-level masked accumulate (registers, static
// indices) -> shfl reduce -> LDS -> 12 global atomics per block.
// ---------------------------------------------------------------------------
__global__ __launch_bounds__(256)
void pair_kernel(const u16* __restrict__ zbf, const float* __restrict__ sq,
                 const int* __restrict__ rres, float* __restrict__ gsum,
                 u32* __restrict__ gcnt)
{
    __shared__ __align__(16) u16 As[128 * 64];   // [row][k] 64 bf16 per row
    __shared__ __align__(16) u16 Bs[128 * 64];
    __shared__ float sqI[128], sqJ[128];
    __shared__ int   rI[128], rJ[128];
    __shared__ unsigned char lut[MOD3];
    __shared__ float bsum[NLEV];
    __shared__ u32   bcnt[NLEV];

    const int tid  = threadIdx.x;
    const int lane = tid & 63;
    const int wave = tid >> 6;

    // linear block id -> (bi, bj), bi <= bj
    int t = blockIdx.x, bi = 0, rem = NBLK;
    while (t >= rem) { t -= rem; ++bi; rem = NBLK - bi; }
    const int bj = bi + t;
    const int I0 = bi * 128, J0 = bj * 128;

    if (tid < 128)      { sqI[tid] = sq[I0 + tid];       rI[tid] = rres[I0 + tid]; }
    else                { int s = tid - 128; sqJ[s] = sq[J0 + s]; rJ[s] = rres[J0 + s]; }
    for (int m = tid; m < MOD3; m += 256) {
        int v = NLEV, x = m;
        if (m != 0) { v = 0; while (x % 3 == 0) { x /= 3; ++v; } }
        lut[m] = (unsigned char)v;
    }
    if (tid < NLEV) { bsum[tid] = 0.f; bcnt[tid] = 0u; }

    const int wr = wave >> 1, wc = wave & 1;

    f32x4 acc[4][4];
#pragma unroll
    for (int m = 0; m < 4; ++m)
#pragma unroll
        for (int n = 0; n < 4; ++n) acc[m][n] = (f32x4){0.f, 0.f, 0.f, 0.f};

    const u16* Abase = zbf + (size_t)I0 * DIM;
    const u16* Bbase = zbf + (size_t)J0 * DIM;

    for (int kt = 0; kt < DIM / 64; ++kt) {
        __syncthreads();   // previous compute done reading LDS
        // stage A and B tiles: 16 chunks of 1 KB each (8 rows x 64 bf16); wave w
        // stages chunks 4w..4w+3. Lane l -> row chunk*8 + (l>>3), col (l&7)*8.
        const int colu = kt * 64 + (lane & 7) * 8;
        const int rsub = lane >> 3;
#pragma unroll
        for (int c4 = 0; c4 < 4; ++c4) {
            const int chunk = wave * 4 + c4;
            const int rowt  = chunk * 8 + rsub;
            const u16* gA = Abase + (size_t)rowt * DIM + colu;
            const u16* gB = Bbase + (size_t)rowt * DIM + colu;
            __builtin_amdgcn_global_load_lds(
                (const __attribute__((address_space(1))) u32*)gA,
                (__attribute__((address_space(3))) u32*)&As[chunk * 512], 16, 0, 0);
            __builtin_amdgcn_global_load_lds(
                (const __attribute__((address_space(1))) u32*)gB,
                (__attribute__((address_space(3))) u32*)&Bs[chunk * 512], 16, 0, 0);
        }
        __syncthreads();   // staging complete (vmcnt drained by barrier)

#pragma unroll
        for (int ks = 0; ks < 2; ++ks) {
            const int k0 = ks * 32 + (lane >> 4) * 8;
            const int rA = lane & 15;
            bf16x8 a[4], b[4];
#pragma unroll
            for (int m = 0; m < 4; ++m)
                a[m] = *reinterpret_cast<const bf16x8*>(&As[(wr * 64 + m * 16 + rA) * 64 + k0]);
#pragma unroll
            for (int n = 0; n < 4; ++n)
                b[n] = *reinterpret_cast<const bf16x8*>(&Bs[(wc * 64 + n * 16 + rA) * 64 + k0]);
#pragma unroll
            for (int m = 0; m < 4; ++m)
#pragma unroll
                for (int n = 0; n < 4; ++n)
                    acc[m][n] = __builtin_amdgcn_mfma_f32_16x16x32_bf16(a[m], b[n], acc[m][n], 0, 0, 0);
        }
    }

    // ---- fused epilogue ----
    float lsum[NLEV] = {0.f, 0.f, 0.f, 0.f, 0.f, 0.f};
    u32   lcnt[NLEV] = {0u, 0u, 0u, 0u, 0u, 0u};
    const int rbase = (lane >> 4) * 4;   // C/D: row = (lane>>4)*4 + q, col = lane&15
    const int cbase = lane & 15;
#pragma unroll
    for (int m = 0; m < 4; ++m) {
        const int il0 = wr * 64 + m * 16 + rbase;
#pragma unroll
        for (int n = 0; n < 4; ++n) {
            const int jl = wc * 64 + n * 16 + cbase;
            const int jg = J0 + jl;
            const float sqj = sqJ[jl];
            const int   rj  = rJ[jl];
#pragma unroll
            for (int q = 0; q < 4; ++q) {
                const int il = il0 + q;
                const int ig = I0 + il;
                if (jg > ig) {
                    const float dot  = acc[m][n][q];
                    float d2 = sqI[il] + sqj - 2.0f * dot;
                    d2 = fmaxf(d2, 0.f);
                    const float dist = sqrtf(d2);
                    int dm = rI[il] - rj;
                    dm += (dm >> 31) & MOD3;        // mod 729 into [0,729)
                    const int v = lut[dm];          // 6 == over-cap / diff==0 -> no level
                    float tv = 1.0f;
                    tv = (v == 1) ? (1.f / 3.f)   : tv;
                    tv = (v == 2) ? (1.f / 9.f)   : tv;
                    tv = (v == 3) ? (1.f / 27.f)  : tv;
                    tv = (v == 4) ? (1.f / 81.f)  : tv;
                    tv = (v == 5) ? (1.f / 243.f) : tv;
                    const float dd  = dist - tv;
                    const float sqd = dd * dd;
#pragma unroll
                    for (int vv = 0; vv < NLEV; ++vv) {
                        const bool hit = (v == vv);
                        lsum[vv] += hit ? sqd : 0.f;
                        lcnt[vv] += hit ? 1u : 0u;
                    }
                }
            }
        }
    }

    // wave shuffle reduce, then LDS, then global atomics
#pragma unroll
    for (int vv = 0; vv < NLEV; ++vv) {
        float s = lsum[vv];
        u32   c = lcnt[vv];
#pragma unroll
        for (int off = 32; off > 0; off >>= 1) {
            s += __shfl_xor(s, off, 64);
            c += __shfl_xor(c, off, 64);
        }
        if (lane == 0) { atomicAdd(&bsum[vv], s); atomicAdd(&bcnt[vv], c); }
    }
    __syncthreads();
    if (tid < NLEV) {
        atomicAdd(&gsum[tid], bsum[tid]);
        atomicAdd(&gcnt[tid], bcnt[tid]);
    }
}

// ---------------------------------------------------------------------------
__global__ void finalize_kernel(const float* __restrict__ gsum,
                                const u32* __restrict__ gcnt,
                                float* __restrict__ out)
{
    if (blockIdx.x == 0 && threadIdx.x == 0) {
        const float w[NLEV] = {1.f, 1.f / 2.f, 1.f / 3.f, 1.f / 4.f, 1.f / 5.f, 1.f / 6.f};
        float total = 0.f, lc = 0.f;
#pragma unroll
        for (int v = 0; v < NLEV; ++v) {
            const float cnt = (float)gcnt[v];
            const float mse = gsum[v] / fmaxf(cnt, 1.f);
            const bool  use = gcnt[v] >= 2u;
            total += use ? w[v] * mse : 0.f;
            lc    += use ? 1.f : 0.f;
        }
        out[0] = total / fmaxf(lc, 1.f);
    }
}

// ---------------------------------------------------------------------------
extern "C" void kernel_launch(void* const* d_in, const int* in_sizes, int n_in,
                              void* d_out, int out_size, void* d_ws, size_t ws_size,
                              hipStream_t stream)
{
    const float* z   = (const float*)d_in[0];
    const int*   idx = (const int*)d_in[1];
    char* ws = (char*)d_ws;
    u16*   zbf  = (u16*)(ws + WS_ZBF);
    float* sq   = (float*)(ws + WS_SQ);
    int*   rres = (int*)(ws + WS_R);
    float* gsum = (float*)(ws + WS_ACC);
    u32*   gcnt = (u32*)(ws + WS_ACC + NLEV * 4);
    float* out  = (float*)d_out;

    prep_kernel<<<N_ROWS, 64, 0, stream>>>(z, idx, zbf, sq, rres, gsum, gcnt);
    pair_kernel<<<NBLK * (NBLK + 1) / 2, 256, 0, stream>>>(zbf, sq, rres, gsum, gcnt);
    finalize_kernel<<<1, 64, 0, stream>>>(gsum, gcnt, out);
}